// Round 4
// baseline (233.404 us; speedup 1.0000x reference)
//
#include <hip/hip_runtime.h>

typedef __bf16 bf16;
typedef __bf16 bf16x4 __attribute__((ext_vector_type(4)));
typedef __bf16 bf16x8 __attribute__((ext_vector_type(8)));
typedef float  f32x4  __attribute__((ext_vector_type(4)));

// ---------------------------------------------------------------- helpers
__device__ __forceinline__ void gld16(const void* g, void* l) {
  __builtin_amdgcn_global_load_lds(
      (const __attribute__((address_space(1))) void*)g,
      (__attribute__((address_space(3))) void*)l, 16, 0, 0);
}

// ---------------------------------------------------------------- fused fp32 -> bf16 (all three tensors, one launch)
__global__ void f2bf_all(const float* __restrict__ x, bf16* __restrict__ xo,
                         const float* __restrict__ w1, bf16* __restrict__ w1o,
                         const float* __restrict__ w2, bf16* __restrict__ w2o) {
  int i = blockIdx.x * blockDim.x + threadIdx.x;   // grid covers 2097152 float4s
  const float* in; bf16* out; int idx;
  if (i < 1048576)      { in = x;  out = xo;  idx = i; }
  else if (i < 1835008) { in = w1; out = w1o; idx = i - 1048576; }
  else                  { in = w2; out = w2o; idx = i - 1835008; }
  float4 v = reinterpret_cast<const float4*>(in)[idx];
  bf16x4 o = { (bf16)v.x, (bf16)v.y, (bf16)v.z, (bf16)v.w };
  reinterpret_cast<bf16x4*>(out)[idx] = o;
}

// ---------------------------------------------------------------- GEMM: C[M,N] = A[M,K] * B[N,K]^T + bias
// MODE 0 (BN=128): QKV epilogue. Q/K scatter to [sec][B*H][S][64] (q scaled
//   by 0.125*log2e); V section writes V^T into the V-third of QKV as
//   [B*H][64][2048] (4 consecutive s at fixed d = one bf16x4 store).
// MODE 1 (BN=64): out-proj epilogue -> fp32 C += bias
template<int MODE, int BN>
__global__ __launch_bounds__(256)
void gemm_bt(const bf16* __restrict__ A, const bf16* __restrict__ B,
             const float* __restrict__ bias, void* __restrict__ Cout,
             int K, int N) {
  __shared__ bf16 As[128 * 64];
  __shared__ bf16 Bs[BN * 64];
  const int tid  = threadIdx.x;
  const int wave = tid >> 6, lane = tid & 63;
  const int quad = lane >> 4, l16 = lane & 15;
  const int bm = blockIdx.x * 128, bn = blockIdx.y * BN;
  constexpr int NI  = (BN == 128) ? 4 : 2;
  constexpr int BCH = BN / 32;
  const int wr = (BN == 128) ? (wave >> 1) * 64 : wave * 32;
  const int wc = (BN == 128) ? (wave & 1) * 64 : 0;
  const int arow = lane >> 3;
  const int acol = (lane & 7) * 8;

  f32x4 acc[NI][4] = {};

  const bf16* Ab = A + (size_t)bm * K;
  const bf16* Bb = B + (size_t)bn * K;

  for (int k0 = 0; k0 < K; k0 += 64) {
#pragma unroll
    for (int i = 0; i < 4; ++i) {
      int c = wave * 4 + i;
      gld16(Ab + (size_t)(c * 8 + arow) * K + k0 + acol, As + c * 512);
    }
#pragma unroll
    for (int i = 0; i < BCH; ++i) {
      int c = wave * BCH + i;
      gld16(Bb + (size_t)(c * 8 + arow) * K + k0 + acol, Bs + c * 512);
    }
    __syncthreads();
#pragma unroll
    for (int kk = 0; kk < 64; kk += 32) {
      bf16x8 af[NI], bfr[4];
#pragma unroll
      for (int i = 0; i < NI; ++i)
        af[i]  = *(const bf16x8*)(As + (wr + i * 16 + l16) * 64 + kk + quad * 8);
#pragma unroll
      for (int j = 0; j < 4; ++j)
        bfr[j] = *(const bf16x8*)(Bs + (wc + j * 16 + l16) * 64 + kk + quad * 8);
#pragma unroll
      for (int i = 0; i < NI; ++i)
#pragma unroll
        for (int j = 0; j < 4; ++j)
          acc[i][j] = __builtin_amdgcn_mfma_f32_16x16x32_bf16(af[i], bfr[j], acc[i][j], 0, 0, 0);
    }
    __syncthreads();
  }

  if constexpr (MODE == 0) {
    bf16* Q = (bf16*)Cout;  // [3][32][2048][64]; V-third holds V^T [32][64][2048]
#pragma unroll
    for (int j = 0; j < 4; ++j) {
      int col = bn + wc + j * 16 + l16;
      float bv  = bias[col];
      int sec = col >> 10, rem = col & 1023;
      int h = rem >> 6, d = rem & 63;
      if (sec < 2) {
        float scl = (sec == 0) ? 0.125f * 1.44269504f : 1.0f;
#pragma unroll
        for (int i = 0; i < NI; ++i) {
#pragma unroll
          for (int r = 0; r < 4; ++r) {
            int row = bm + wr + i * 16 + quad * 4 + r;
            int b = row >> 11, si = row & 2047;
            float v = (acc[i][j][r] + bv) * scl;
            Q[(((size_t)sec * 32 + b * 16 + h) * 2048 + si) * 64 + d] = (bf16)v;
          }
        }
      } else {
#pragma unroll
        for (int i = 0; i < NI; ++i) {
          int row0 = bm + wr + i * 16 + quad * 4;
          int b = row0 >> 11, si = row0 & 2047;
          bf16x4 pk = { (bf16)(acc[i][j][0] + bv), (bf16)(acc[i][j][1] + bv),
                        (bf16)(acc[i][j][2] + bv), (bf16)(acc[i][j][3] + bv) };
          *(bf16x4*)(Q + (size_t)2 * 4194304 +
                     ((size_t)(b * 16 + h) * 64 + d) * 2048 + si) = pk;
        }
      }
    }
  } else {
    float* C = (float*)Cout;
#pragma unroll
    for (int j = 0; j < 4; ++j) {
      int col = bn + wc + j * 16 + l16;
      float bv = bias[col];
#pragma unroll
      for (int i = 0; i < NI; ++i)
#pragma unroll
        for (int r = 0; r < 4; ++r) {
          int row = bm + wr + i * 16 + quad * 4 + r;
          C[(size_t)row * N + col] = acc[i][j][r] + bv;
        }
    }
  }
}

// ---------------------------------------------------------------- flash attention v12 = v11 + split-KV x2 (flash-decoding)
// History: v8 78.5us (2 blk/CU, grid-limited). v9 half-tile 136us (killed
// MFMA amortization). v10 194us (launch_bounds cap -> spills). v11 76.8us:
// LDS 53KB allows 3 blk/CU but GRID = 512 = 2/CU exactly -> occupancy
// still 18%. The grid, not LDS, is the limiter.
// v12: split the KV loop across 2 blocks (grid 32x16x2 = 1024 = exactly
// 4/CU). Each block does 8 K-tiles, writes UNNORMALIZED f32 partial O and
// partial row-sum l; combine kernel computes (O0+O1)/(l0+l1) -> bf16 At.
// Per-wave tile shape unchanged (32 q-rows, KV tile 128). To fit 4 blk/CU
// LDS must be <= 40KB: Ps halved by chunking PV (write P cols 0-63, PV
// kk 0-1; reuse buffer for cols 64-127, PV kk 2-3; per-wave buffer, WAR
// ordered by in-order DS + exact aliasing). LDS = Ks 128x72 + Ps 4x32x72
// = 36,864B -> 4 blk/CU = 16 waves/CU (VGPR 124 <= 128 gives 4 w/SIMD).
// Same S^T-form QK, single-buffer Ks (v11), Q frags in regs, V direct
// from global V^T, XCD-local grid (blk%8 = bh%8 for all z).
__global__ __launch_bounds__(256, 2)
void attn_kernel(const bf16* __restrict__ QKV, const bf16* __restrict__ Vt,
                 float* __restrict__ Opart, float* __restrict__ lpart) {
  __shared__ bf16 Ks[128 * 72];
  __shared__ bf16 Ps[4][32 * 72];

  const int bh = blockIdx.x;               // XCD-locality: bh is the fast dim
  const int q0 = blockIdx.y * 128;
  const int half = blockIdx.z;             // KV split: tiles [half*8, half*8+8)
  const int kt0 = half * 8;
  const bf16* Qg = QKV + ((size_t)bh * 2048 + q0) * 64;
  const bf16* Kg = QKV + (size_t)32 * 2048 * 64 + (size_t)bh * 2048 * 64;
  const bf16* Vg = Vt + (size_t)bh * 64 * 2048;
  float* Oh = Opart + (size_t)half * 4194304 + (size_t)bh * 2048 * 64;
  float* lh = lpart + (size_t)half * 65536 + (size_t)bh * 2048;

  const int tid  = threadIdx.x;
  const int wave = tid >> 6, lane = tid & 63;
  const int quad = lane >> 4, l16 = lane & 15;
  const int srow = tid >> 3;            // 0..31 staging row
  const int scol = (tid & 7) * 8;       // 0..56 staging col
  bf16* Pw = &Ps[wave][0];

  // Q fragments in registers (B-operand), reused across the 8 K-tiles
  bf16x8 aq[2][2];
#pragma unroll
  for (int i = 0; i < 2; ++i)
#pragma unroll
    for (int kh = 0; kh < 2; ++kh)
      aq[i][kh] = *(const bf16x8*)(Qg + (size_t)(wave * 32 + i * 16 + l16) * 64 +
                                   kh * 32 + quad * 8);

  // preload first K tile of this half into Ks
  {
    bf16x8 kreg[4];
#pragma unroll
    for (int ch = 0; ch < 4; ++ch)
      kreg[ch] = *(const bf16x8*)(Kg + (size_t)(kt0 * 128 + ch * 32 + srow) * 64 + scol);
#pragma unroll
    for (int ch = 0; ch < 4; ++ch)
      *(bf16x8*)(&Ks[(ch * 32 + srow) * 72 + scol]) = kreg[ch];
  }
  __syncthreads();

  float rs[2] = {0.f, 0.f};             // per-lane partial row sums (qrow = i*16+l16)
  f32x4 o[2][4] = {};

  for (int kt = 0; kt < 8; ++kt) {
    const int g = kt0 + kt;             // global K-tile index

    // prefetch next K tile to regs (independent of LDS)
    bf16x8 kreg[4];
    if (kt < 7) {
#pragma unroll
      for (int ch = 0; ch < 4; ++ch)
        kreg[ch] = *(const bf16x8*)(Kg + (size_t)((g + 1) * 128 + ch * 32 + srow) * 64 + scol);
    }
    // prefetch V fragments for this tile
    bf16x8 bv[4][4];
#pragma unroll
    for (int kk = 0; kk < 4; ++kk)
#pragma unroll
      for (int oj = 0; oj < 4; ++oj)
        bv[kk][oj] = *(const bf16x8*)(Vg + (size_t)(oj * 16 + l16) * 2048 +
                                      g * 128 + kk * 32 + quad * 8);

    // ---- S^T = K Q^T : lane holds S[qrow=l16][kcol=ni*16+quad*4+r]
    f32x4 s[2][8] = {};
#pragma unroll
    for (int kh = 0; kh < 2; ++kh) {
#pragma unroll
      for (int ni = 0; ni < 8; ++ni) {
        bf16x8 bk = *(const bf16x8*)(&Ks[(ni * 16 + l16) * 72 + kh * 32 + quad * 8]);
        s[0][ni] = __builtin_amdgcn_mfma_f32_16x16x32_bf16(bk, aq[0][kh], s[0][ni], 0, 0, 0);
        s[1][ni] = __builtin_amdgcn_mfma_f32_16x16x32_bf16(bk, aq[1][kh], s[1][ni], 0, 0, 0);
      }
    }

    __syncthreads();   // all waves done READING Ks -> safe to overwrite

    // write next K tile into Ks (latency hidden under exp2/P/PV below)
    if (kt < 7) {
#pragma unroll
      for (int ch = 0; ch < 4; ++ch)
        *(bf16x8*)(&Ks[(ch * 32 + srow) * 72 + scol]) = kreg[ch];
    }

    // ---- chunked P/PV: halve Ps by reusing the 64-col buffer twice.
    // chunk c covers kcols [c*64, c*64+64) = ni c*4..c*4+3 = kk c*2..c*2+1.
#pragma unroll
    for (int c = 0; c < 2; ++c) {
#pragma unroll
      for (int i = 0; i < 2; ++i)
#pragma unroll
        for (int nc = 0; nc < 4; ++nc) {
          int ni = c * 4 + nc;
          float p0 = __builtin_amdgcn_exp2f(s[i][ni][0]);
          float p1 = __builtin_amdgcn_exp2f(s[i][ni][1]);
          float p2 = __builtin_amdgcn_exp2f(s[i][ni][2]);
          float p3 = __builtin_amdgcn_exp2f(s[i][ni][3]);
          rs[i] += (p0 + p1) + (p2 + p3);
          bf16x4 pk = { (bf16)p0, (bf16)p1, (bf16)p2, (bf16)p3 };
          *(bf16x4*)(Pw + (i * 16 + l16) * 72 + nc * 16 + quad * 4) = pk;
        }
      // O += P V for this chunk (per-wave Ps; lgkmcnt orders write->read)
#pragma unroll
      for (int kc = 0; kc < 2; ++kc) {
        int kk = c * 2 + kc;
#pragma unroll
        for (int i = 0; i < 2; ++i) {
          bf16x8 ap = *(const bf16x8*)(Pw + (i * 16 + l16) * 72 + kc * 32 + quad * 8);
#pragma unroll
          for (int oj = 0; oj < 4; ++oj)
            o[i][oj] = __builtin_amdgcn_mfma_f32_16x16x32_bf16(ap, bv[kk][oj], o[i][oj], 0, 0, 0);
        }
      }
    }

    __syncthreads();   // Ks writes visible to all waves before next QK
  }

  // ---- finalize row sums: quads hold partials for row l16
#pragma unroll
  for (int i = 0; i < 2; ++i) {
    rs[i] += __shfl_xor(rs[i], 16);
    rs[i] += __shfl_xor(rs[i], 32);
  }

  // ---- epilogue: write UNNORMALIZED f32 partial O + partial row sums
#pragma unroll
  for (int i = 0; i < 2; ++i) {
    if (quad == 0)
      lh[q0 + wave * 32 + i * 16 + l16] = rs[i];
#pragma unroll
    for (int r = 0; r < 4; ++r) {
      int row = q0 + wave * 32 + i * 16 + quad * 4 + r;
#pragma unroll
      for (int oj = 0; oj < 4; ++oj)
        Oh[(size_t)row * 64 + oj * 16 + l16] = o[i][oj][r];
    }
  }
}

// ---------------------------------------------------------------- combine: At = (O0+O1)/(l0+l1), scatter to [B,S,1024] bf16
__global__ void attn_combine(const float* __restrict__ O0, const float* __restrict__ O1,
                             const float* __restrict__ l0, const float* __restrict__ l1,
                             bf16* __restrict__ At) {
  int i = blockIdx.x * blockDim.x + threadIdx.x;   // 1,048,576 f32x4 groups
  int rid = i >> 4, d4 = i & 15;                   // rid = bh*2048+s
  float inv = 1.0f / (l0[rid] + l1[rid]);
  f32x4 a = reinterpret_cast<const f32x4*>(O0)[i];
  f32x4 b = reinterpret_cast<const f32x4*>(O1)[i];
  int bh = rid >> 11, s = rid & 2047;
  int bb = bh >> 4, h = bh & 15;
  bf16x4 ov = { (bf16)((a[0] + b[0]) * inv), (bf16)((a[1] + b[1]) * inv),
                (bf16)((a[2] + b[2]) * inv), (bf16)((a[3] + b[3]) * inv) };
  *reinterpret_cast<bf16x4*>(At + ((size_t)(bb * 2048 + s)) * 1024 + h * 64 + d4 * 4) = ov;
}

// ---------------------------------------------------------------- launch
extern "C" void kernel_launch(void* const* d_in, const int* in_sizes, int n_in,
                              void* d_out, int out_size, void* d_ws, size_t ws_size,
                              hipStream_t stream) {
  const float* x      = (const float*)d_in[0];   // [2,2048,1024]
  const float* qkv_w  = (const float*)d_in[1];   // [3072,1024]
  const float* qkv_b  = (const float*)d_in[2];   // [3072]
  const float* out_w  = (const float*)d_in[3];   // [1024,1024]
  const float* out_b  = (const float*)d_in[4];   // [1024]
  float* out = (float*)d_out;                    // [2,2048,1024] fp32

  char* ws = (char*)d_ws;
  bf16* Xb    = (bf16*)(ws);                     // 8 MB
  bf16* Wqkv  = (bf16*)(ws + 8388608);           // 6 MB
  bf16* Wout  = (bf16*)(ws + 14680064);          // 2 MB
  bf16* QKV   = (bf16*)(ws + 16777216);          // 24 MB: [Q][K] + V^T third
  bf16* At    = (bf16*)(ws + 41943040);          // 8 MB attn output [B,S,1024]
  float* Opart = (float*)(ws + 50331648);        // 2 x 16 MB f32 partial O
  float* lpart = (float*)(ws + 83886080);        // 2 x 256 KB f32 partial sums
  bf16* VtP   = QKV + (size_t)2 * 32 * 2048 * 64; // V^T [32][64][2048]

  f2bf_all<<<8192, 256, 0, stream>>>(x, Xb, qkv_w, Wqkv, out_w, Wout);

  gemm_bt<0, 128><<<dim3(32, 24), 256, 0, stream>>>(Xb, Wqkv, qkv_b, (void*)QKV, 1024, 3072);

  // grid (bh, q_tile, kv_half): blk%8 = bh%8 -> per-head XCD locality
  attn_kernel<<<dim3(32, 16, 2), 256, 0, stream>>>(QKV, VtP, Opart, lpart);

  attn_combine<<<4096, 256, 0, stream>>>(Opart, Opart + 4194304,
                                         lpart, lpart + 65536, At);

  gemm_bt<1, 64><<<dim3(32, 16), 256, 0, stream>>>(At, Wout, out_b, (void*)out, 1024, 1024);
}